// Round 15
// baseline (143.381 us; speedup 1.0000x reference)
//
#include <hip/hip_runtime.h>
#include <stdint.h>

#define LOG2E 1.44269504088896340736f

typedef __bf16 v8bf __attribute__((ext_vector_type(8)));
typedef _Float16 v8h __attribute__((ext_vector_type(8)));
typedef float f32x4 __attribute__((ext_vector_type(4)));
typedef float f32x16 __attribute__((ext_vector_type(16)));
typedef unsigned int v4u __attribute__((ext_vector_type(4)));
typedef unsigned int v2u __attribute__((ext_vector_type(2)));

// ---------- helpers ----------
__device__ __forceinline__ unsigned short f2bf(float f) {
  union { float f; uint32_t u; } v; v.f = f;
  uint32_t u = v.u;
  uint32_t r = (u + 0x7FFFu + ((u >> 16) & 1u)) >> 16;   // RN-even
  return (unsigned short)r;
}
__device__ __forceinline__ void gll16(const void* g, void* l) {
  __builtin_amdgcn_global_load_lds(
      (const __attribute__((address_space(1))) unsigned int*)g,
      (__attribute__((address_space(3))) unsigned int*)l, 16, 0, 0);
}
__device__ __forceinline__ uint32_t pk2(float a, float b) {
  union { __bf16 h[2]; uint32_t u; } x;
  x.h[0] = (__bf16)a; x.h[1] = (__bf16)b;
  return x.u;
}

// Permuted QKV column order c':
//   c' in [0,1536): h = c'>>7, j = c'&127  -> orig n = h*192 + j   (q|k)
//   c' in [1536,2304): h = (c'-1536)>>6, d = (..)&63 -> n = h*192+128+d (v)

// ---------- fused prep: Ah (x fp16), Whk (qk cols fp16, permuted), Wv (fp16), WoT (bf16) ----------
__global__ void prep_fused(const float* __restrict__ x, const float* __restrict__ Wqkv,
                           const float* __restrict__ Wout,
                           _Float16* __restrict__ Ah,
                           _Float16* __restrict__ Whk,
                           _Float16* __restrict__ Wv,
                           unsigned short* __restrict__ WoT) {
  const int t = threadIdx.x, f = blockIdx.x;
  if (f < 12288) {                    // Ah: x -> fp16
    int m = f / 3, n = (f - m * 3) * 256 + t;
    Ah[(size_t)m * 768 + n] = (_Float16)x[(size_t)m * 768 + n];
  } else if (f < 19200) {             // Wqkv columns (permuted)
    int g = f - 12288;
    int cp = g / 3, k = (g - cp * 3) * 256 + t;
    int n;
    if (cp < 1536) n = (cp >> 7) * 192 + (cp & 127);
    else           n = ((cp - 1536) >> 6) * 192 + 128 + ((cp - 1536) & 63);
    float v = Wqkv[(size_t)k * 2304 + n];
    if (cp < 1536) Whk[(size_t)cp * 768 + k] = (_Float16)v;
    else           Wv[(size_t)(cp - 1536) * 768 + k] = (_Float16)v;
  } else {                            // Wout^T plain bf16
    int g = f - 19200;
    int n = g / 3, k = (g - n * 3) * 256 + t;
    WoT[(size_t)n * 768 + k] = f2bf(Wout[(size_t)k * 768 + n]);
  }
}

// ---------- fused QKV GEMM (fp16, K=768) + split epilogues ----------
__global__ __launch_bounds__(256) void gemm_qkv(
    const _Float16* __restrict__ Ah, const _Float16* __restrict__ Whk,
    const _Float16* __restrict__ Wv, const float* __restrict__ bqkv,
    _Float16* __restrict__ Qh, _Float16* __restrict__ Kh,
    unsigned short* __restrict__ VT) {
  __shared__ _Float16 As[128 * 32];
  __shared__ _Float16 Bs[128 * 32];
  const int t = threadIdx.x, f = blockIdx.x;
  const int w = t >> 6, l = t & 63, lr = l & 15, lg = l >> 4;
  const int wm = (w >> 1) * 64, wn = (w & 1) * 64;
  f32x4 acc[4][4] = {};

  if (f < 384) {
    // ---- q|k path ----
    const int xcd = f & 7, s = f >> 3;
    const int m0 = (xcd * 4 + (s & 3)) * 128;
    const int xt = s >> 2;                       // head 0..11
    const _Float16* Ap = Ah + (size_t)m0 * 768;
    const _Float16* Bp = Whk + (size_t)xt * 128 * 768;
    for (int kt = 0; kt < 24; ++kt) {
      const int k0 = kt << 5;
      const int c0 = t, c1 = t + 256;
      gll16(Ap + (size_t)(c0 >> 2) * 768 + k0 + ((c0 & 3) << 3), &As[c0 * 8]);
      gll16(Ap + (size_t)(c1 >> 2) * 768 + k0 + ((c1 & 3) << 3), &As[c1 * 8]);
      gll16(Bp + (size_t)(c0 >> 2) * 768 + k0 + ((c0 & 3) << 3), &Bs[c0 * 8]);
      gll16(Bp + (size_t)(c1 >> 2) * 768 + k0 + ((c1 & 3) << 3), &Bs[c1 * 8]);
      __syncthreads();
      v8h a[4], b[4];
#pragma unroll
      for (int i = 0; i < 4; i++) {
        a[i] = *(const v8h*)&As[(wm + i * 16 + lr) * 32 + lg * 8];
        b[i] = *(const v8h*)&Bs[(wn + i * 16 + lr) * 32 + lg * 8];
      }
#pragma unroll
      for (int i = 0; i < 4; i++)
#pragma unroll
        for (int j = 0; j < 4; j++)
          acc[i][j] = __builtin_amdgcn_mfma_f32_16x16x32_f16(a[i], b[j], acc[i][j], 0, 0, 0);
      __syncthreads();
    }
#pragma unroll
    for (int j = 0; j < 4; j++) {
      const int jj = j * 16 + lr;                // 0..63 within q or k
      const float bv = bqkv[xt * 192 + wn + jj];
#pragma unroll
      for (int i = 0; i < 4; i++) {
#pragma unroll
        for (int r = 0; r < 4; r++) {
          const int m = m0 + wm + i * 16 + lg * 4 + r;
          const int b = m >> 11, p = m & 2047;
          size_t base = ((size_t)(b * 12 + xt) * 2048 + p) * 64;
          float val = acc[i][j][r] + bv;
          if (wn == 0) Qh[base + jj] = (_Float16)(val * (8.0f * LOG2E));
          else         Kh[base + jj] = (_Float16)val;
        }
      }
    }
  } else {
    // ---- v path, transposed: C'[d][m] = Wv x Ah^T ----
    const int g = f - 384;
    const int xcd = g & 7, s = g >> 3;           // s 0..23
    const int m0v = (xcd * 4 + (s & 3)) * 128;   // m-tile 0..31
    const int d0 = (s >> 2) * 128;               // d-tile 0..5
    for (int kt = 0; kt < 24; ++kt) {
      const int k0 = kt << 5;
      const int c0 = t, c1 = t + 256;
      gll16(Wv + (size_t)(d0 + (c0 >> 2)) * 768 + k0 + ((c0 & 3) << 3), &As[c0 * 8]);
      gll16(Wv + (size_t)(d0 + (c1 >> 2)) * 768 + k0 + ((c1 & 3) << 3), &As[c1 * 8]);
      gll16(Ah + (size_t)(m0v + (c0 >> 2)) * 768 + k0 + ((c0 & 3) << 3), &Bs[c0 * 8]);
      gll16(Ah + (size_t)(m0v + (c1 >> 2)) * 768 + k0 + ((c1 & 3) << 3), &Bs[c1 * 8]);
      __syncthreads();
      v8h a[4], b[4];
#pragma unroll
      for (int i = 0; i < 4; i++) {
        a[i] = *(const v8h*)&As[(wm + i * 16 + lr) * 32 + lg * 8];
        b[i] = *(const v8h*)&Bs[(wn + i * 16 + lr) * 32 + lg * 8];
      }
#pragma unroll
      for (int i = 0; i < 4; i++)
#pragma unroll
        for (int j = 0; j < 4; j++)
          acc[i][j] = __builtin_amdgcn_mfma_f32_16x16x32_f16(a[i], b[j], acc[i][j], 0, 0, 0);
      __syncthreads();
    }
#pragma unroll
    for (int i = 0; i < 4; i++) {
#pragma unroll
      for (int r = 0; r < 4; r++) {
        const int drow = d0 + wm + i * 16 + lg * 4 + r;
        const int h = drow >> 6, dd = drow & 63;
        const float bv = bqkv[h * 192 + 128 + dd];
#pragma unroll
        for (int j = 0; j < 4; j++) {
          const int m = m0v + wn + j * 16 + lr;
          const int b = m >> 11, p = m & 2047;
          VT[((size_t)(b * 12 + h) * 64 + dd) * 2048 + p] = f2bf(acc[i][j][r] + bv);
        }
      }
    }
  }
}

// ---------- out-proj GEMM: 64x128 tiles, 384 blocks (bf16) ----------
__global__ __launch_bounds__(256) void gemm_out(
    const unsigned short* __restrict__ A, const unsigned short* __restrict__ B,
    const float* __restrict__ bias, float* __restrict__ C) {
  __shared__ unsigned short As[64 * 32];
  __shared__ unsigned short Bs[128 * 32];
  const int t = threadIdx.x, f = blockIdx.x;
  const int xcd = f & 7, s = f >> 3;             // s 0..47
  const int m0 = (xcd * 8 + (s & 7)) * 64;       // 64 m-tiles
  const int n0 = (s >> 3) * 128;                 // 6 n-tiles
  const int w = t >> 6, l = t & 63, lr = l & 15, lg = l >> 4;
  const int wm = (w >> 1) * 32, wn = (w & 1) * 64;
  f32x4 acc[2][4] = {};
  for (int kt = 0; kt < 24; ++kt) {
    const int k0 = kt << 5;
    gll16(A + (size_t)(m0 + (t >> 2)) * 768 + k0 + ((t & 3) << 3), &As[t * 8]);
    gll16(B + (size_t)(n0 + (t >> 2)) * 768 + k0 + ((t & 3) << 3), &Bs[t * 8]);
    gll16(B + (size_t)(n0 + 64 + (t >> 2)) * 768 + k0 + ((t & 3) << 3), &Bs[(t + 256) * 8]);
    __syncthreads();
    v8bf a[2], b[4];
#pragma unroll
    for (int i = 0; i < 2; i++)
      a[i] = *(const v8bf*)&As[(wm + i * 16 + lr) * 32 + lg * 8];
#pragma unroll
    for (int j = 0; j < 4; j++)
      b[j] = *(const v8bf*)&Bs[(wn + j * 16 + lr) * 32 + lg * 8];
#pragma unroll
    for (int i = 0; i < 2; i++)
#pragma unroll
      for (int j = 0; j < 4; j++)
        acc[i][j] = __builtin_amdgcn_mfma_f32_16x16x32_bf16(a[i], b[j], acc[i][j], 0, 0, 0);
    __syncthreads();
  }
#pragma unroll
  for (int i = 0; i < 2; i++) {
#pragma unroll
    for (int j = 0; j < 4; j++) {
      const int col = n0 + wn + j * 16 + lr;
      const float bv = bias[col];
#pragma unroll
      for (int r = 0; r < 4; r++) {
        const int row = m0 + wm + i * 16 + lg * 4 + r;
        C[(size_t)row * 768 + col] = acc[i][j][r] + bv;
      }
    }
  }
}

// ---------- flash attention: fp16 QK^T, KVBLK=64, split-K x4 ----------
// Flat grid 1536 = 8 xcd x 24 pairGroups x 16 q-tiles; 4-resident + 2-queued
// blocks/CU (R14 lesson: resident waves, not tail, drive perf). NKT=8 tiles
// of 64 keys per split. One softmax pass per 64 keys (halved fixed overhead),
// 8 barriers/block. Softmax in log2 domain; PV bf16.
__global__ __launch_bounds__(256, 4) void attn(
    const _Float16* __restrict__ Qh, const _Float16* __restrict__ Kh,
    const unsigned short* __restrict__ VT,
    float* __restrict__ Op, float* __restrict__ Ml) {
  __shared__ __align__(16) _Float16 Ks[2][64 * 64];
  __shared__ __align__(16) unsigned short Vs[2][64 * 64];
  __shared__ float Al[4][32];
  const int t = threadIdx.x, w = t >> 6, l = t & 63;
  const int lq = l & 31, hi = l >> 5;
  const int f = blockIdx.x;
  const int xcd = f & 7, slot = f >> 3;
  const int p = xcd + 8 * (slot >> 4);      // 0..95: (bh,split) pair
  const int bh = p >> 2, zsplit = p & 3;
  const int q0 = (slot & 15) * 128;
  const int qw0 = q0 + w * 32;
  const int NKT = 8;
  const int ktBase = zsplit * 8;            // 8 key-tiles of 64 keys per split
  const _Float16* Qb = Qh + (size_t)bh * 2048 * 64;
  const _Float16* Kb = Kh + (size_t)bh * 2048 * 64;
  const unsigned short* Vb = VT + (size_t)bh * 64 * 2048;

  // swizzled LDS write offsets (element units): rows are 64 elems (128 B)
  int kwofs[2], vwofs[2];
#pragma unroll
  for (int i = 0; i < 2; i++) {
    int c = t + i * 256;                    // 8 chunks per row, 64 rows
    int row = c >> 3, part = c & 7;
    kwofs[i] = (row * 64 + part * 8) ^ ((row & 7) << 3);
    vwofs[i] = kwofs[i];                    // same geometry for V
  }

  // linear global source pointers (coalesced), bumped per kt
  const char* gK = (const char*)Kb + (size_t)ktBase * 8192 + (size_t)t * 16;
  const char* gV = (const char*)Vb + (size_t)(t >> 3) * 4096 + (size_t)(t & 7) * 16
                   + (size_t)ktBase * 128;

  v4u kreg[2], vreg[2];
#pragma unroll
  for (int i = 0; i < 2; i++) {
    kreg[i] = *(const v4u*)(gK + i * 4096);      // rows 0-31 then 32-63
    vreg[i] = *(const v4u*)(gV + i * 131072);    // d 0-31 then 32-63
  }
#pragma unroll
  for (int i = 0; i < 2; i++) {
    *(v4u*)&Ks[0][kwofs[i]] = kreg[i];
    *(v4u*)&Vs[0][vwofs[i]] = vreg[i];
  }
  gK += 8192; gV += 128;
#pragma unroll
  for (int i = 0; i < 2; i++) {
    kreg[i] = *(const v4u*)(gK + i * 4096);
    vreg[i] = *(const v4u*)(gV + i * 131072);
  }

  // Q B-frags (fp16): lane holds Q[qw0+lq][ks*16 + hi*8 .. +7]
  v8h qf[4];
#pragma unroll
  for (int ks = 0; ks < 4; ++ks)
    qf[ks] = *(const v8h*)(Qb + (size_t)(qw0 + lq) * 64 + ks * 16 + hi * 8);

  f32x16 o0 = {}, o1 = {};
  float mrun = -1e30f, lsum = 0.f;
  const int sx = (lq & 7) << 3;             // read swizzle (rows = lq / lq+32)
  __syncthreads();

  for (int kt = 0; kt < NKT; ++kt) {
    const _Float16* ksb = &Ks[kt & 1][0];
    const unsigned short* vsb = &Vs[kt & 1][0];
    _Float16* ksw = &Ks[(kt & 1) ^ 1][0];
    unsigned short* vsw = &Vs[(kt & 1) ^ 1][0];

    // S^T(log2) = K Q^T : s0 = keys 0-31, s1 = keys 32-63
    f32x16 s0 = {}, s1 = {};
    __builtin_amdgcn_s_setprio(1);
#pragma unroll
    for (int ks = 0; ks < 4; ++ks) {
      v8h ka = *(const v8h*)&ksb[((lq) * 64 + ks * 16 + hi * 8) ^ sx];
      v8h kb = *(const v8h*)&ksb[((lq + 32) * 64 + ks * 16 + hi * 8) ^ sx];
      s0 = __builtin_amdgcn_mfma_f32_32x32x16_f16(ka, qf[ks], s0, 0, 0, 0);
      s1 = __builtin_amdgcn_mfma_f32_32x32x16_f16(kb, qf[ks], s1, 0, 0, 0);
    }
    __builtin_amdgcn_s_setprio(0);

    // stage tile kt+1 into the other buffer (overlaps compute)
    if (kt < NKT - 1) {
#pragma unroll
      for (int i = 0; i < 2; i++) {
        *(v4u*)&ksw[kwofs[i]] = kreg[i];
        *(v4u*)&vsw[vwofs[i]] = vreg[i];
      }
    }
    if (kt < NKT - 2) {
      gK += 8192; gV += 128;
#pragma unroll
      for (int i = 0; i < 2; i++) {
        kreg[i] = *(const v4u*)(gK + i * 4096);
        vreg[i] = *(const v4u*)(gV + i * 131072);
      }
    }

    // lane-local max over 32 values (tree) + one half-swap
    float tm[16];
#pragma unroll
    for (int i = 0; i < 16; i++) tm[i] = fmaxf(s0[i], s1[i]);
#pragma unroll
    for (int i = 0; i < 8; i++) tm[i] = fmaxf(tm[i], tm[i + 8]);
#pragma unroll
    for (int i = 0; i < 4; i++) tm[i] = fmaxf(tm[i], tm[i + 4]);
    float pmax = fmaxf(fmaxf(tm[0], tm[1]), fmaxf(tm[2], tm[3]));
    {
      v2u r = __builtin_amdgcn_permlane32_swap(__float_as_uint(pmax),
                                               __float_as_uint(pmax), false, false);
      pmax = fmaxf(__uint_as_float(r.x), __uint_as_float(r.y));
    }

    // T13 defer-max, THR=32 (log2 units)
    if (__any(pmax > mrun + 32.f)) {
      float mnew = fmaxf(mrun, pmax);
      float a = __builtin_exp2f(mrun - mnew);
      mrun = mnew;
      lsum *= a;
      if (!hi) Al[w][lq] = a;
#pragma unroll
      for (int r = 0; r < 16; r++) {
        float ar = Al[w][(r & 3) + 8 * (r >> 2) + 4 * hi];
        o0[r] *= ar; o1[r] *= ar;
      }
    }

    // P = exp2(S - m) in-place, tree sum, pack PV A-frags
#pragma unroll
    for (int i = 0; i < 16; i++) s0[i] = __builtin_exp2f(s0[i] - mrun);
#pragma unroll
    for (int i = 0; i < 16; i++) s1[i] = __builtin_exp2f(s1[i] - mrun);
    {
      float a0 = (s0[0] + s0[8]) + (s0[1] + s0[9]) + (s1[0] + s1[8]) + (s1[1] + s1[9]);
      float a1 = (s0[2] + s0[10]) + (s0[3] + s0[11]) + (s1[2] + s1[10]) + (s1[3] + s1[11]);
      float a2 = (s0[4] + s0[12]) + (s0[5] + s0[13]) + (s1[4] + s1[12]) + (s1[5] + s1[13]);
      float a3 = (s0[6] + s0[14]) + (s0[7] + s0[15]) + (s1[6] + s1[14]) + (s1[7] + s1[15]);
      float ps = (a0 + a1) + (a2 + a3);
      v2u r = __builtin_amdgcn_permlane32_swap(__float_as_uint(ps),
                                               __float_as_uint(ps), false, false);
      lsum += __uint_as_float(r.x) + __uint_as_float(r.y);
    }
    uint32_t paw[4][4];
    {
      v2u r0 = __builtin_amdgcn_permlane32_swap(pk2(s0[0], s0[1]), pk2(s0[4], s0[5]), false, false);
      v2u r1 = __builtin_amdgcn_permlane32_swap(pk2(s0[2], s0[3]), pk2(s0[6], s0[7]), false, false);
      paw[0][0] = r0.x; paw[0][2] = r0.y; paw[0][1] = r1.x; paw[0][3] = r1.y;
      v2u r2 = __builtin_amdgcn_permlane32_swap(pk2(s0[8], s0[9]), pk2(s0[12], s0[13]), false, false);
      v2u r3 = __builtin_amdgcn_permlane32_swap(pk2(s0[10], s0[11]), pk2(s0[14], s0[15]), false, false);
      paw[1][0] = r2.x; paw[1][2] = r2.y; paw[1][1] = r3.x; paw[1][3] = r3.y;
      v2u r4 = __builtin_amdgcn_permlane32_swap(pk2(s1[0], s1[1]), pk2(s1[4], s1[5]), false, false);
      v2u r5 = __builtin_amdgcn_permlane32_swap(pk2(s1[2], s1[3]), pk2(s1[6], s1[7]), false, false);
      paw[2][0] = r4.x; paw[2][2] = r4.y; paw[2][1] = r5.x; paw[2][3] = r5.y;
      v2u r6 = __builtin_amdgcn_permlane32_swap(pk2(s1[8], s1[9]), pk2(s1[12], s1[13]), false, false);
      v2u r7 = __builtin_amdgcn_permlane32_swap(pk2(s1[10], s1[11]), pk2(s1[14], s1[15]), false, false);
      paw[3][0] = r6.x; paw[3][2] = r6.y; paw[3][1] = r7.x; paw[3][3] = r7.y;
    }

    // O += P V  (bf16; V^T rows = d, 64-key tile -> 4 A-frags)
    __builtin_amdgcn_s_setprio(1);
#pragma unroll
    for (int ks = 0; ks < 4; ++ks) {
      union { uint32_t u[4]; v8bf v; } pa;
      pa.u[0] = paw[ks][0]; pa.u[1] = paw[ks][1];
      pa.u[2] = paw[ks][2]; pa.u[3] = paw[ks][3];
      v8bf v0 = *(const v8bf*)&vsb[((lq) * 64 + ks * 16 + hi * 8) ^ sx];
      v8bf v1 = *(const v8bf*)&vsb[((lq + 32) * 64 + ks * 16 + hi * 8) ^ sx];
      o0 = __builtin_amdgcn_mfma_f32_32x32x16_bf16(pa.v, v0, o0, 0, 0, 0);
      o1 = __builtin_amdgcn_mfma_f32_32x32x16_bf16(pa.v, v1, o1, 0, 0, 0);
    }
    __builtin_amdgcn_s_setprio(0);
    if (kt < NKT - 1) __syncthreads();
  }

  // epilogue: partial O + (m in log2 units, l)
  const size_t S = (size_t)24 * 2048;
  const size_t srow = (size_t)zsplit * S + (size_t)bh * 2048;
  if (!hi) {
    Ml[(srow + qw0 + lq) * 2]     = mrun;
    Ml[(srow + qw0 + lq) * 2 + 1] = lsum;
  }
#pragma unroll
  for (int r = 0; r < 16; r++) {
    const int q = qw0 + (r & 3) + 8 * (r >> 2) + 4 * hi;
    Op[(srow + q) * 64 + lq]      = o0[r];
    Op[(srow + q) * 64 + 32 + lq] = o1[r];
  }
}

// ---------- combine the four split-K partials (m in log2 units) ----------
__global__ __launch_bounds__(256) void attn_combine(
    const float* __restrict__ Op, const float* __restrict__ Ml,
    __bf16* __restrict__ Oe) {
  const size_t S = (size_t)24 * 2048;
  int row = blockIdx.x * 4 + (threadIdx.x >> 6);   // bh*2048 + q
  int lane = threadIdx.x & 63;
  int bh = row >> 11, q = row & 2047;
  int b = bh / 12, h = bh - b * 12;
  float m[4], lv[4];
#pragma unroll
  for (int s = 0; s < 4; s++) {
    m[s]  = Ml[(s * S + row) * 2];
    lv[s] = Ml[(s * S + row) * 2 + 1];
  }
  float M = fmaxf(fmaxf(m[0], m[1]), fmaxf(m[2], m[3]));
  float num = 0.f, den = 0.f;
#pragma unroll
  for (int s = 0; s < 4; s++) {
    float a = __builtin_exp2f(m[s] - M);
    den += lv[s] * a;
    num += Op[(s * S + row) * 64 + lane] * a;
  }
  Oe[((size_t)(b * 2048 + q)) * 768 + h * 64 + lane] = (__bf16)(num / den);
}

// ---------- launcher ----------
extern "C" void kernel_launch(void* const* d_in, const int* in_sizes, int n_in,
                              void* d_out, int out_size, void* d_ws, size_t ws_size,
                              hipStream_t stream) {
  const float* x    = (const float*)d_in[0];
  const float* Wqkv = (const float*)d_in[1];
  const float* bqkv = (const float*)d_in[2];
  const float* Wout = (const float*)d_in[3];
  const float* bout = (const float*)d_in[4];
  float* out = (float*)d_out;
  char* ws = (char*)d_ws;

  _Float16*       Ah    = (_Float16*)(ws + 0);                // 6.3 MB (dead after gemm_qkv)
  _Float16*       Whk   = (_Float16*)(ws + 18874368);         // 2.36 MB (dead after gemm_qkv)
  _Float16*       Wv    = (_Float16*)(ws + 25952256);         // 1.18 MB (dead after gemm_qkv)
  _Float16*       Qh    = (_Float16*)(ws + 67239936);         // 6.3 MB
  _Float16*       Kh    = (_Float16*)(ws + 86114304);         // 6.3 MB
  unsigned short* VT    = (unsigned short*)(ws + 104988672);  // 6.3 MB
  unsigned short* Oemb  = (unsigned short*)(ws + 111280128);  // 6.3 MB
  unsigned short* WoT   = (unsigned short*)(ws + 117571584);  // 1.2 MB
  // split-K partials alias the dead Ah/Whk/Wv region (attn runs after gemm_qkv):
  float*          Opart = (float*)(ws + 0);                   // 4 x 12.58 MB = 50.3 MB
  float*          Mlpart= (float*)(ws + 52428800);            // 1.6 MB (dead region)

  prep_fused<<<dim3(21504), 256, 0, stream>>>(x, Wqkv, Wout, Ah, Whk, Wv, WoT);
  gemm_qkv<<<dim3(576), 256, 0, stream>>>(Ah, Whk, Wv, bqkv, Qh, Kh, VT);
  attn<<<dim3(1536), 256, 0, stream>>>(Qh, Kh, VT, Opart, Mlpart);
  attn_combine<<<dim3(12288), 256, 0, stream>>>(Opart, Mlpart, (__bf16*)Oemb);
  gemm_out<<<dim3(384), 256, 0, stream>>>(Oemb, WoT, bout, out);
}

// Round 16
// 136.600 us; speedup vs baseline: 1.0496x; 1.0496x over previous
//
#include <hip/hip_runtime.h>
#include <stdint.h>

#define LOG2E 1.44269504088896340736f

typedef __bf16 v8bf __attribute__((ext_vector_type(8)));
typedef _Float16 v8h __attribute__((ext_vector_type(8)));
typedef float f32x4 __attribute__((ext_vector_type(4)));
typedef float f32x16 __attribute__((ext_vector_type(16)));
typedef unsigned int v4u __attribute__((ext_vector_type(4)));
typedef unsigned int v2u __attribute__((ext_vector_type(2)));

// ---------- helpers ----------
__device__ __forceinline__ unsigned short f2bf(float f) {
  union { float f; uint32_t u; } v; v.f = f;
  uint32_t u = v.u;
  uint32_t r = (u + 0x7FFFu + ((u >> 16) & 1u)) >> 16;   // RN-even
  return (unsigned short)r;
}
__device__ __forceinline__ void gll16(const void* g, void* l) {
  __builtin_amdgcn_global_load_lds(
      (const __attribute__((address_space(1))) unsigned int*)g,
      (__attribute__((address_space(3))) unsigned int*)l, 16, 0, 0);
}
__device__ __forceinline__ uint32_t pk2(float a, float b) {
  union { __bf16 h[2]; uint32_t u; } x;
  x.h[0] = (__bf16)a; x.h[1] = (__bf16)b;
  return x.u;
}

// Permuted QKV column order c':
//   c' in [0,1536): h = c'>>7, j = c'&127  -> orig n = h*192 + j   (q|k)
//   c' in [1536,2304): h = (c'-1536)>>6, d = (..)&63 -> n = h*192+128+d (v)

// ---------- fused prep: Ah (x fp16), Whk (qk cols fp16, permuted), Wv (fp16), WoT (bf16) ----------
__global__ void prep_fused(const float* __restrict__ x, const float* __restrict__ Wqkv,
                           const float* __restrict__ Wout,
                           _Float16* __restrict__ Ah,
                           _Float16* __restrict__ Whk,
                           _Float16* __restrict__ Wv,
                           unsigned short* __restrict__ WoT) {
  const int t = threadIdx.x, f = blockIdx.x;
  if (f < 12288) {                    // Ah: x -> fp16
    int m = f / 3, n = (f - m * 3) * 256 + t;
    Ah[(size_t)m * 768 + n] = (_Float16)x[(size_t)m * 768 + n];
  } else if (f < 19200) {             // Wqkv columns (permuted)
    int g = f - 12288;
    int cp = g / 3, k = (g - cp * 3) * 256 + t;
    int n;
    if (cp < 1536) n = (cp >> 7) * 192 + (cp & 127);
    else           n = ((cp - 1536) >> 6) * 192 + 128 + ((cp - 1536) & 63);
    float v = Wqkv[(size_t)k * 2304 + n];
    if (cp < 1536) Whk[(size_t)cp * 768 + k] = (_Float16)v;
    else           Wv[(size_t)(cp - 1536) * 768 + k] = (_Float16)v;
  } else {                            // Wout^T plain bf16
    int g = f - 19200;
    int n = g / 3, k = (g - n * 3) * 256 + t;
    WoT[(size_t)n * 768 + k] = f2bf(Wout[(size_t)k * 768 + n]);
  }
}

// ---------- fused QKV GEMM (fp16, K=768) + split epilogues ----------
__global__ __launch_bounds__(256) void gemm_qkv(
    const _Float16* __restrict__ Ah, const _Float16* __restrict__ Whk,
    const _Float16* __restrict__ Wv, const float* __restrict__ bqkv,
    _Float16* __restrict__ Qh, _Float16* __restrict__ Kh,
    unsigned short* __restrict__ VT) {
  __shared__ _Float16 As[128 * 32];
  __shared__ _Float16 Bs[128 * 32];
  const int t = threadIdx.x, f = blockIdx.x;
  const int w = t >> 6, l = t & 63, lr = l & 15, lg = l >> 4;
  const int wm = (w >> 1) * 64, wn = (w & 1) * 64;
  f32x4 acc[4][4] = {};

  if (f < 384) {
    // ---- q|k path ----
    const int xcd = f & 7, s = f >> 3;
    const int m0 = (xcd * 4 + (s & 3)) * 128;
    const int xt = s >> 2;                       // head 0..11
    const _Float16* Ap = Ah + (size_t)m0 * 768;
    const _Float16* Bp = Whk + (size_t)xt * 128 * 768;
    for (int kt = 0; kt < 24; ++kt) {
      const int k0 = kt << 5;
      const int c0 = t, c1 = t + 256;
      gll16(Ap + (size_t)(c0 >> 2) * 768 + k0 + ((c0 & 3) << 3), &As[c0 * 8]);
      gll16(Ap + (size_t)(c1 >> 2) * 768 + k0 + ((c1 & 3) << 3), &As[c1 * 8]);
      gll16(Bp + (size_t)(c0 >> 2) * 768 + k0 + ((c0 & 3) << 3), &Bs[c0 * 8]);
      gll16(Bp + (size_t)(c1 >> 2) * 768 + k0 + ((c1 & 3) << 3), &Bs[c1 * 8]);
      __syncthreads();
      v8h a[4], b[4];
#pragma unroll
      for (int i = 0; i < 4; i++) {
        a[i] = *(const v8h*)&As[(wm + i * 16 + lr) * 32 + lg * 8];
        b[i] = *(const v8h*)&Bs[(wn + i * 16 + lr) * 32 + lg * 8];
      }
#pragma unroll
      for (int i = 0; i < 4; i++)
#pragma unroll
        for (int j = 0; j < 4; j++)
          acc[i][j] = __builtin_amdgcn_mfma_f32_16x16x32_f16(a[i], b[j], acc[i][j], 0, 0, 0);
      __syncthreads();
    }
#pragma unroll
    for (int j = 0; j < 4; j++) {
      const int jj = j * 16 + lr;                // 0..63 within q or k
      const float bv = bqkv[xt * 192 + wn + jj];
#pragma unroll
      for (int i = 0; i < 4; i++) {
#pragma unroll
        for (int r = 0; r < 4; r++) {
          const int m = m0 + wm + i * 16 + lg * 4 + r;
          const int b = m >> 11, p = m & 2047;
          size_t base = ((size_t)(b * 12 + xt) * 2048 + p) * 64;
          float val = acc[i][j][r] + bv;
          if (wn == 0) Qh[base + jj] = (_Float16)(val * (8.0f * LOG2E));
          else         Kh[base + jj] = (_Float16)val;
        }
      }
    }
  } else {
    // ---- v path, transposed: C'[d][m] = Wv x Ah^T ----
    const int g = f - 384;
    const int xcd = g & 7, s = g >> 3;           // s 0..23
    const int m0v = (xcd * 4 + (s & 3)) * 128;   // m-tile 0..31
    const int d0 = (s >> 2) * 128;               // d-tile 0..5
    for (int kt = 0; kt < 24; ++kt) {
      const int k0 = kt << 5;
      const int c0 = t, c1 = t + 256;
      gll16(Wv + (size_t)(d0 + (c0 >> 2)) * 768 + k0 + ((c0 & 3) << 3), &As[c0 * 8]);
      gll16(Wv + (size_t)(d0 + (c1 >> 2)) * 768 + k0 + ((c1 & 3) << 3), &As[c1 * 8]);
      gll16(Ah + (size_t)(m0v + (c0 >> 2)) * 768 + k0 + ((c0 & 3) << 3), &Bs[c0 * 8]);
      gll16(Ah + (size_t)(m0v + (c1 >> 2)) * 768 + k0 + ((c1 & 3) << 3), &Bs[c1 * 8]);
      __syncthreads();
      v8h a[4], b[4];
#pragma unroll
      for (int i = 0; i < 4; i++) {
        a[i] = *(const v8h*)&As[(wm + i * 16 + lr) * 32 + lg * 8];
        b[i] = *(const v8h*)&Bs[(wn + i * 16 + lr) * 32 + lg * 8];
      }
#pragma unroll
      for (int i = 0; i < 4; i++)
#pragma unroll
        for (int j = 0; j < 4; j++)
          acc[i][j] = __builtin_amdgcn_mfma_f32_16x16x32_f16(a[i], b[j], acc[i][j], 0, 0, 0);
      __syncthreads();
    }
#pragma unroll
    for (int i = 0; i < 4; i++) {
#pragma unroll
      for (int r = 0; r < 4; r++) {
        const int drow = d0 + wm + i * 16 + lg * 4 + r;
        const int h = drow >> 6, dd = drow & 63;
        const float bv = bqkv[h * 192 + 128 + dd];
#pragma unroll
        for (int j = 0; j < 4; j++) {
          const int m = m0v + wn + j * 16 + lr;
          const int b = m >> 11, p = m & 2047;
          VT[((size_t)(b * 12 + h) * 64 + dd) * 2048 + p] = f2bf(acc[i][j][r] + bv);
        }
      }
    }
  }
}

// ---------- out-proj GEMM: 64x128 tiles, 384 blocks (bf16) ----------
__global__ __launch_bounds__(256) void gemm_out(
    const unsigned short* __restrict__ A, const unsigned short* __restrict__ B,
    const float* __restrict__ bias, float* __restrict__ C) {
  __shared__ unsigned short As[64 * 32];
  __shared__ unsigned short Bs[128 * 32];
  const int t = threadIdx.x, f = blockIdx.x;
  const int xcd = f & 7, s = f >> 3;             // s 0..47
  const int m0 = (xcd * 8 + (s & 7)) * 64;       // 64 m-tiles
  const int n0 = (s >> 3) * 128;                 // 6 n-tiles
  const int w = t >> 6, l = t & 63, lr = l & 15, lg = l >> 4;
  const int wm = (w >> 1) * 32, wn = (w & 1) * 64;
  f32x4 acc[2][4] = {};
  for (int kt = 0; kt < 24; ++kt) {
    const int k0 = kt << 5;
    gll16(A + (size_t)(m0 + (t >> 2)) * 768 + k0 + ((t & 3) << 3), &As[t * 8]);
    gll16(B + (size_t)(n0 + (t >> 2)) * 768 + k0 + ((t & 3) << 3), &Bs[t * 8]);
    gll16(B + (size_t)(n0 + 64 + (t >> 2)) * 768 + k0 + ((t & 3) << 3), &Bs[(t + 256) * 8]);
    __syncthreads();
    v8bf a[2], b[4];
#pragma unroll
    for (int i = 0; i < 2; i++)
      a[i] = *(const v8bf*)&As[(wm + i * 16 + lr) * 32 + lg * 8];
#pragma unroll
    for (int j = 0; j < 4; j++)
      b[j] = *(const v8bf*)&Bs[(wn + j * 16 + lr) * 32 + lg * 8];
#pragma unroll
    for (int i = 0; i < 2; i++)
#pragma unroll
      for (int j = 0; j < 4; j++)
        acc[i][j] = __builtin_amdgcn_mfma_f32_16x16x32_bf16(a[i], b[j], acc[i][j], 0, 0, 0);
    __syncthreads();
  }
#pragma unroll
  for (int i = 0; i < 2; i++) {
#pragma unroll
    for (int j = 0; j < 4; j++) {
      const int col = n0 + wn + j * 16 + lr;
      const float bv = bias[col];
#pragma unroll
      for (int r = 0; r < 4; r++) {
        const int row = m0 + wm + i * 16 + lg * 4 + r;
        C[(size_t)row * 768 + col] = acc[i][j][r] + bv;
      }
    }
  }
}

// ---------- flash attention: fp16 QK^T (K=64), KVBLK=32, split-K x4 ----------
// R13-proven config: flat grid 1536 = 8 xcd x 24 pairGroups x 16 q-tiles;
// NKT=16 tiles of 32 keys per split; 4 waves/SIMD; log2-domain softmax.
// Op partials stored bf16 (0.4% rel err on partials -> ~0.01 absmax added).
__global__ __launch_bounds__(256, 4) void attn(
    const _Float16* __restrict__ Qh, const _Float16* __restrict__ Kh,
    const unsigned short* __restrict__ VT,
    __bf16* __restrict__ Op, float* __restrict__ Ml) {
  __shared__ __align__(16) _Float16 Ks[2][32 * 64];
  __shared__ __align__(16) unsigned short Vs[2][64 * 32];
  __shared__ float Al[4][32];
  const int t = threadIdx.x, w = t >> 6, l = t & 63;
  const int lq = l & 31, hi = l >> 5;
  const int f = blockIdx.x;
  const int xcd = f & 7, slot = f >> 3;
  const int p = xcd + 8 * (slot >> 4);      // 0..95: (bh,split) pair
  const int bh = p >> 2, zsplit = p & 3;
  const int q0 = (slot & 15) * 128;
  const int qw0 = q0 + w * 32;
  const int NKT = 16;
  const int ktBase = zsplit * 16;           // 16 key-tiles of 32 keys per split
  const _Float16* Qb = Qh + (size_t)bh * 2048 * 64;
  const _Float16* Kb = Kh + (size_t)bh * 2048 * 64;
  const unsigned short* Vb = VT + (size_t)bh * 64 * 2048;

  // swizzled LDS write offsets (element units)
  const int krow = t >> 3, kpart = t & 7;   // 8 chunks per 64-elem fp16 K row
  const int kwofs = (krow * 64 + kpart * 8) ^ ((krow & 7) << 3);
  const int vd = t >> 2, vpart = t & 3;     // 4 chunks per 32-elem V row
  const int vwofs = (vd * 32 + vpart * 8) ^ ((vd & 3) << 3);

  // linear global source pointers (coalesced), bumped per kt
  const char* gK = (const char*)Kb + (size_t)ktBase * 4096 + (size_t)t * 16;
  const char* gV = (const char*)Vb + (size_t)vd * 4096 + (size_t)vpart * 16
                   + (size_t)ktBase * 64;

  v4u kreg, vreg;
  kreg = *(const v4u*)gK;
  vreg = *(const v4u*)gV;
  *(v4u*)&Ks[0][kwofs] = kreg;
  *(v4u*)&Vs[0][vwofs] = vreg;
  gK += 4096; gV += 64;
  kreg = *(const v4u*)gK;
  vreg = *(const v4u*)gV;

  // Q B-frags (fp16): lane holds Q[qw0+lq][ks*16 + hi*8 .. +7]
  v8h qf[4];
#pragma unroll
  for (int ks = 0; ks < 4; ++ks)
    qf[ks] = *(const v8h*)(Qb + (size_t)(qw0 + lq) * 64 + ks * 16 + hi * 8);

  f32x16 o0 = {}, o1 = {};
  float mrun = -1e30f, lsum = 0.f;
  const int sxk = (lq & 7) << 3;            // K read swizzle (rows = lq)
  const int sxv = (lq & 3) << 3;            // V read swizzle (rows = lq, lq+32)
  __syncthreads();

  for (int kt = 0; kt < NKT; ++kt) {
    const _Float16* ksb = &Ks[kt & 1][0];
    const unsigned short* vsb = &Vs[kt & 1][0];
    _Float16* ksw = &Ks[(kt & 1) ^ 1][0];
    unsigned short* vsw = &Vs[(kt & 1) ^ 1][0];

    // S^T(log2) = K Q^T  (fp16, K=64 -> 4 MFMA)
    f32x16 s = {};
    __builtin_amdgcn_s_setprio(1);
#pragma unroll
    for (int ks = 0; ks < 4; ++ks) {
      v8h ka = *(const v8h*)&ksb[(lq * 64 + ks * 16 + hi * 8) ^ sxk];
      s = __builtin_amdgcn_mfma_f32_32x32x16_f16(ka, qf[ks], s, 0, 0, 0);
    }
    __builtin_amdgcn_s_setprio(0);

    // stage tile kt+1 into the other buffer (overlaps compute)
    if (kt < NKT - 1) {
      *(v4u*)&ksw[kwofs] = kreg;
      *(v4u*)&vsw[vwofs] = vreg;
    }
    if (kt < NKT - 2) {
      gK += 4096; gV += 64;
      kreg = *(const v4u*)gK;
      vreg = *(const v4u*)gV;
    }

    // lane-local max (tree) + one half-swap
    float tm[8];
#pragma unroll
    for (int i = 0; i < 8; i++) tm[i] = fmaxf(s[i], s[i + 8]);
#pragma unroll
    for (int i = 0; i < 4; i++) tm[i] = fmaxf(tm[i], tm[i + 4]);
    float pmax = fmaxf(fmaxf(tm[0], tm[1]), fmaxf(tm[2], tm[3]));
    {
      v2u r = __builtin_amdgcn_permlane32_swap(__float_as_uint(pmax),
                                               __float_as_uint(pmax), false, false);
      pmax = fmaxf(__uint_as_float(r.x), __uint_as_float(r.y));
    }

    // T13 defer-max, THR=32 (log2 units)
    if (__any(pmax > mrun + 32.f)) {
      float mnew = fmaxf(mrun, pmax);
      float a = __builtin_exp2f(mrun - mnew);
      mrun = mnew;
      lsum *= a;
      if (!hi) Al[w][lq] = a;
#pragma unroll
      for (int r = 0; r < 16; r++) {
        float ar = Al[w][(r & 3) + 8 * (r >> 2) + 4 * hi];
        o0[r] *= ar; o1[r] *= ar;
      }
    }

    // P = exp2(S - m) in-place, tree sum, pack PV A-frags
#pragma unroll
    for (int i = 0; i < 16; i++) s[i] = __builtin_exp2f(s[i] - mrun);
    {
      float a0 = (s[0] + s[8]) + (s[1] + s[9]);
      float a1 = (s[2] + s[10]) + (s[3] + s[11]);
      float a2 = (s[4] + s[12]) + (s[5] + s[13]);
      float a3 = (s[6] + s[14]) + (s[7] + s[15]);
      float ps = (a0 + a1) + (a2 + a3);
      v2u r = __builtin_amdgcn_permlane32_swap(__float_as_uint(ps),
                                               __float_as_uint(ps), false, false);
      lsum += __uint_as_float(r.x) + __uint_as_float(r.y);
    }
    uint32_t paw[2][4];
    {
      v2u r0 = __builtin_amdgcn_permlane32_swap(pk2(s[0], s[1]), pk2(s[4], s[5]), false, false);
      v2u r1 = __builtin_amdgcn_permlane32_swap(pk2(s[2], s[3]), pk2(s[6], s[7]), false, false);
      paw[0][0] = r0.x; paw[0][2] = r0.y; paw[0][1] = r1.x; paw[0][3] = r1.y;
      v2u r2 = __builtin_amdgcn_permlane32_swap(pk2(s[8], s[9]), pk2(s[12], s[13]), false, false);
      v2u r3 = __builtin_amdgcn_permlane32_swap(pk2(s[10], s[11]), pk2(s[14], s[15]), false, false);
      paw[1][0] = r2.x; paw[1][2] = r2.y; paw[1][1] = r3.x; paw[1][3] = r3.y;
    }

    // O += P V  (bf16)
    __builtin_amdgcn_s_setprio(1);
#pragma unroll
    for (int ks = 0; ks < 2; ++ks) {
      union { uint32_t u[4]; v8bf v; } pa;
      pa.u[0] = paw[ks][0]; pa.u[1] = paw[ks][1];
      pa.u[2] = paw[ks][2]; pa.u[3] = paw[ks][3];
      v8bf v0 = *(const v8bf*)&vsb[(lq * 32 + ks * 16 + hi * 8) ^ sxv];
      v8bf v1 = *(const v8bf*)&vsb[((lq + 32) * 32 + ks * 16 + hi * 8) ^ sxv];
      o0 = __builtin_amdgcn_mfma_f32_32x32x16_bf16(pa.v, v0, o0, 0, 0, 0);
      o1 = __builtin_amdgcn_mfma_f32_32x32x16_bf16(pa.v, v1, o1, 0, 0, 0);
    }
    __builtin_amdgcn_s_setprio(0);
    if (kt < NKT - 1) __syncthreads();
  }

  // epilogue: partial O (bf16) + (m in log2 units, l)
  const size_t S = (size_t)24 * 2048;
  const size_t srow = (size_t)zsplit * S + (size_t)bh * 2048;
  if (!hi) {
    Ml[(srow + qw0 + lq) * 2]     = mrun;
    Ml[(srow + qw0 + lq) * 2 + 1] = lsum;
  }
#pragma unroll
  for (int r = 0; r < 16; r++) {
    const int q = qw0 + (r & 3) + 8 * (r >> 2) + 4 * hi;
    Op[(srow + q) * 64 + lq]      = (__bf16)o0[r];
    Op[(srow + q) * 64 + 32 + lq] = (__bf16)o1[r];
  }
}

// ---------- combine the four split-K partials (bf16 Op, m in log2 units) ----------
__global__ __launch_bounds__(256) void attn_combine(
    const __bf16* __restrict__ Op, const float* __restrict__ Ml,
    __bf16* __restrict__ Oe) {
  const size_t S = (size_t)24 * 2048;
  int row = blockIdx.x * 4 + (threadIdx.x >> 6);   // bh*2048 + q
  int lane = threadIdx.x & 63;
  int bh = row >> 11, q = row & 2047;
  int b = bh / 12, h = bh - b * 12;
  float m[4], lv[4];
#pragma unroll
  for (int s = 0; s < 4; s++) {
    m[s]  = Ml[(s * S + row) * 2];
    lv[s] = Ml[(s * S + row) * 2 + 1];
  }
  float M = fmaxf(fmaxf(m[0], m[1]), fmaxf(m[2], m[3]));
  float num = 0.f, den = 0.f;
#pragma unroll
  for (int s = 0; s < 4; s++) {
    float a = __builtin_exp2f(m[s] - M);
    den += lv[s] * a;
    num += (float)Op[(s * S + row) * 64 + lane] * a;
  }
  Oe[((size_t)(b * 2048 + q)) * 768 + h * 64 + lane] = (__bf16)(num / den);
}

// ---------- launcher ----------
extern "C" void kernel_launch(void* const* d_in, const int* in_sizes, int n_in,
                              void* d_out, int out_size, void* d_ws, size_t ws_size,
                              hipStream_t stream) {
  const float* x    = (const float*)d_in[0];
  const float* Wqkv = (const float*)d_in[1];
  const float* bqkv = (const float*)d_in[2];
  const float* Wout = (const float*)d_in[3];
  const float* bout = (const float*)d_in[4];
  float* out = (float*)d_out;
  char* ws = (char*)d_ws;

  _Float16*       Ah    = (_Float16*)(ws + 0);                // 6.3 MB (dead after gemm_qkv)
  _Float16*       Whk   = (_Float16*)(ws + 18874368);         // 2.36 MB (dead after gemm_qkv)
  _Float16*       Wv    = (_Float16*)(ws + 25952256);         // 1.18 MB (dead after gemm_qkv)
  _Float16*       Qh    = (_Float16*)(ws + 67239936);         // 6.3 MB
  _Float16*       Kh    = (_Float16*)(ws + 86114304);         // 6.3 MB
  unsigned short* VT    = (unsigned short*)(ws + 104988672);  // 6.3 MB
  unsigned short* Oemb  = (unsigned short*)(ws + 111280128);  // 6.3 MB
  unsigned short* WoT   = (unsigned short*)(ws + 117571584);  // 1.2 MB
  // split-K partials alias the dead Ah/Whk/Wv region (attn runs after gemm_qkv):
  __bf16*         Opart = (__bf16*)(ws + 0);                  // 4 x 6.29 MB = 25.2 MB
  float*          Mlpart= (float*)(ws + 52428800);            // 1.6 MB (dead region)

  prep_fused<<<dim3(21504), 256, 0, stream>>>(x, Wqkv, Wout, Ah, Whk, Wv, WoT);
  gemm_qkv<<<dim3(576), 256, 0, stream>>>(Ah, Whk, Wv, bqkv, Qh, Kh, VT);
  attn<<<dim3(1536), 256, 0, stream>>>(Qh, Kh, VT, Opart, Mlpart);
  attn_combine<<<dim3(12288), 256, 0, stream>>>(Opart, Mlpart, (__bf16*)Oemb);
  gemm_out<<<dim3(384), 256, 0, stream>>>(Oemb, WoT, bout, out);
}